// Round 6
// baseline (69.102 us; speedup 1.0000x reference)
//
#include <hip/hip_runtime.h>
#include <hip/hip_fp16.h>
#include <math.h>

#define ALPHA 0.001f
#define GAMMA 0.01f
#define DD 784
#define TD 1568          // 2*D floats per template row
#define XF2 392          // f2 per x row
#define NF2 784          // valid f2 per coded row
#define PF2 832          // padded f2 per coded row (13*64)
#define NCHUNK 13
#define MM 256
#define BB 1024
#define NCLS 10
#define ROWS_PB 8

typedef _Float16 v2h __attribute__((ext_vector_type(2)));

// ws layout (floats):
//   [0..255]    per-block partial min of x
//   [256..511]  per-block partial max of x
//   [512..767]  scale[m] = committed ? 1/denom : -1
//   [768]       final min
//   [769]       1/(max-min+1e-10)
//   [800..863]  probe dummy sink

__global__ __launch_bounds__(256) void k_minmax(const float* __restrict__ x,
                                                float* __restrict__ ws,
                                                int* __restrict__ out_bits) {
  const float4* x4 = (const float4*)x;
  const int n4 = BB * DD / 4;  // 200704
  int tid = blockIdx.x * 256 + threadIdx.x;

  if (tid < BB * NCLS) out_bits[tid] = 0xFF800000;  // -inf bits each launch

  float mn = 1e30f, mx = -1e30f;
  for (int i = tid; i < n4; i += 256 * 256) {
    float4 v = x4[i];
    mn = fminf(mn, fminf(fminf(v.x, v.y), fminf(v.z, v.w)));
    mx = fmaxf(mx, fmaxf(fmaxf(v.x, v.y), fmaxf(v.z, v.w)));
  }
#pragma unroll
  for (int off = 32; off; off >>= 1) {
    mn = fminf(mn, __shfl_xor(mn, off, 64));
    mx = fmaxf(mx, __shfl_xor(mx, off, 64));
  }
  __shared__ float smn[4], smx[4];
  int lane = threadIdx.x & 63, wid = threadIdx.x >> 6;
  if (lane == 0) { smn[wid] = mn; smx[wid] = mx; }
  __syncthreads();
  if (threadIdx.x == 0) {
    mn = fminf(fminf(smn[0], smn[1]), fminf(smn[2], smn[3]));
    mx = fmaxf(fmaxf(smx[0], smx[1]), fmaxf(smx[2], smx[3]));
    ws[blockIdx.x] = mn;
    ws[256 + blockIdx.x] = mx;
  }
}

__global__ __launch_bounds__(256) void k_stats(float* __restrict__ ws) {
  int tid = threadIdx.x;
  float mn = ws[tid], mx = ws[256 + tid];
#pragma unroll
  for (int off = 32; off; off >>= 1) {
    mn = fminf(mn, __shfl_xor(mn, off, 64));
    mx = fmaxf(mx, __shfl_xor(mx, off, 64));
  }
  __shared__ float smn[4], smx[4];
  int lane = tid & 63, wid = tid >> 6;
  if (lane == 0) { smn[wid] = mn; smx[wid] = mx; }
  __syncthreads();
  if (tid == 0) {
    mn = fminf(fminf(smn[0], smn[1]), fminf(smn[2], smn[3]));
    mx = fmaxf(fmaxf(smx[0], smx[1]), fmaxf(smx[2], smx[3]));
    ws[768] = mn;
    ws[769] = 1.0f / (mx - mn + 1e-10f);
  }
}

__global__ __launch_bounds__(64) void k_denom(const float* __restrict__ T,
                                              const int* __restrict__ committed,
                                              const int* __restrict__ counts,
                                              float* __restrict__ scale_out) {
  int m = blockIdx.x;
  int lane = threadIdx.x;
  const float4* t4 = (const float4*)(T + m * TD);
  float s = 0.f;
  for (int i = lane; i < TD / 4; i += 64) {
    float4 v = t4[i];
    s += (v.x + v.y) + (v.z + v.w);
  }
#pragma unroll
  for (int off = 32; off; off >>= 1) s += __shfl_xor(s, off, 64);
  if (lane == 0) {
    float denom = ALPHA + s + GAMMA * (float)counts[m];
    scale_out[m] = committed[m] ? (1.0f / denom) : -1.0f;
  }
}

// Clock-calibration probe: 2048 blk x 256 thr x 2048 independent FMAs.
// Predicted 13.7 us @ 2.4 GHz (+~10% loop overhead). Pure VALU, no memory.
__global__ __launch_bounds__(256) void k_probe(float* __restrict__ ws) {
  float a = ws[768], b = ws[769];
  float x0 = a, x1 = a + b, x2 = b, x3 = a * 0.5f;
  float x4 = b * 0.5f, x5 = a + 1.f, x6 = b + 1.f, x7 = a * b;
#pragma unroll 1
  for (int i = 0; i < 256; ++i) {
    x0 = __builtin_fmaf(x0, a, b); x1 = __builtin_fmaf(x1, a, b);
    x2 = __builtin_fmaf(x2, a, b); x3 = __builtin_fmaf(x3, a, b);
    x4 = __builtin_fmaf(x4, a, b); x5 = __builtin_fmaf(x5, a, b);
    x6 = __builtin_fmaf(x6, a, b); x7 = __builtin_fmaf(x7, a, b);
  }
  float s = ((x0 + x1) + (x2 + x3)) + ((x4 + x5) + (x6 + x7));
  if (s > 1e30f) ws[800 + (threadIdx.x & 63)] = s;  // unprovable-dead sink
}

// grid: 2048 blocks = 128 rowgroups x 16 tgroups (bid = rg*16 + tg).
// 512 threads = 8 waves; wave w owns templates {tg*16+2w, tg*16+2w+1}.
// coded rows in LDS as packed half2 (26.6 KB -> 4 blocks/CU, 100% occ).
// Inner op: v_pk_min_f16 + v_dot2_f32_f16 (f32 accumulate).
__global__ __launch_bounds__(512, 8) void k_main(const float* __restrict__ x,
                                                 const float* __restrict__ T,
                                                 const int* __restrict__ labels,
                                                 const float* __restrict__ ws,
                                                 int* __restrict__ out_bits) {
  __shared__ v2h coded[ROWS_PB * PF2];      // 8*832*4 = 26624 B
  __shared__ int clsmax[ROWS_PB][NCLS];

  int tid = threadIdx.x;
  int lane = tid & 63, wid = tid >> 6;
  int rg = blockIdx.x >> 4;
  int tg = blockIdx.x & 15;
  int row0 = rg * ROWS_PB;
  int m0 = tg * 16 + wid * 2;

  float fmn = ws[768], finv = ws[769];
  float scA = ws[512 + m0], scB = ws[512 + m0 + 1];
  int lblA = labels[m0], lblB = labels[m0 + 1];

  if (tid < ROWS_PB * NCLS) clsmax[tid / NCLS][tid % NCLS] = 0xFF800000;

  // ---- phase 1: stage 8 normalized complement-coded rows (half2) ----
#pragma unroll
  for (int r = 0; r < ROWS_PB; ++r) {
    const float2* xr = (const float2*)(x + (size_t)(row0 + r) * DD);
    for (int p = tid; p < PF2; p += 512) {
      float vx, vy;
      if (p < XF2) {
        float2 t = xr[p];
        vx = (t.x - fmn) * finv;  vy = (t.y - fmn) * finv;
      } else if (p < NF2) {
        float2 t = xr[p - XF2];
        vx = 1.f - (t.x - fmn) * finv;  vy = 1.f - (t.y - fmn) * finv;
      } else {
        vx = 0.f; vy = 0.f;
      }
      v2h h; h.x = (_Float16)vx; h.y = (_Float16)vy;
      coded[r * PF2 + p] = h;
    }
  }
  __syncthreads();

  // ---- phase 2: chunk-outer fuzzy-AND, pk_min + dot2 accumulate ----
  float accA[ROWS_PB], accB[ROWS_PB];
#pragma unroll
  for (int r = 0; r < ROWS_PB; ++r) { accA[r] = 0.f; accB[r] = 0.f; }

  const float2* tp0 = (const float2*)(T + (size_t)m0 * TD);
  const float2* tp1 = (const float2*)(T + (size_t)(m0 + 1) * TD);

#pragma unroll 2
  for (int k = 0; k < NCHUNK; ++k) {
    int idx = k * 64 + lane;
    int tidx = (idx > NF2 - 1) ? (NF2 - 1) : idx;  // clamp tail; coded pad=0 -> min()=0
    float2 a2 = tp0[tidx];
    float2 b2 = tp1[tidx];
    v2h tA; tA.x = (_Float16)a2.x; tA.y = (_Float16)a2.y;
    v2h tB; tB.x = (_Float16)b2.x; tB.y = (_Float16)b2.y;
#pragma unroll
    for (int r = 0; r < ROWS_PB; ++r) {
      v2h cv = coded[r * PF2 + idx];
      v2h mA = __builtin_elementwise_min(cv, tA);
      v2h mB = __builtin_elementwise_min(cv, tB);
#if __has_builtin(__builtin_amdgcn_fdot2)
      v2h ones; ones.x = (_Float16)1.f; ones.y = (_Float16)1.f;
      accA[r] = __builtin_amdgcn_fdot2(mA, ones, accA[r], false);
      accB[r] = __builtin_amdgcn_fdot2(mB, ones, accB[r], false);
#else
      accA[r] += (float)mA.x + (float)mA.y;
      accB[r] += (float)mB.x + (float)mB.y;
#endif
    }
  }

  // ---- bulk reduce: 16 independent 64-lane butterflies ----
#pragma unroll
  for (int r = 0; r < ROWS_PB; ++r) {
#pragma unroll
    for (int off = 32; off; off >>= 1) {
      accA[r] += __shfl_xor(accA[r], off, 64);
      accB[r] += __shfl_xor(accB[r], off, 64);
    }
  }
  float vout = 0.f;
#pragma unroll
  for (int r = 0; r < ROWS_PB; ++r) {
    if (lane == r)     vout = accA[r];
    if (lane == 8 + r) vout = accB[r];
  }
  if (lane < 16) {
    float sc = (lane < 8) ? scA : scB;
    int lb   = (lane < 8) ? lblA : lblB;
    if (sc > 0.f) atomicMax(&clsmax[lane & 7][lb], __float_as_int(vout * sc));
  }
  __syncthreads();

  // ---- epilogue: combine across the 16 tgroup blocks ----
  if (tid < ROWS_PB * NCLS) {
    int rr = tid / NCLS, cc = tid - rr * NCLS;
    int bits = clsmax[rr][cc];
    if (bits != 0xFF800000)
      atomicMax(&out_bits[(row0 + rr) * NCLS + cc], bits);
  }
}

extern "C" void kernel_launch(void* const* d_in, const int* in_sizes, int n_in,
                              void* d_out, int out_size, void* d_ws, size_t ws_size,
                              hipStream_t stream) {
  const float* x = (const float*)d_in[0];
  const float* T = (const float*)d_in[1];
  const int* committed = (const int*)d_in[2];
  const int* labels = (const int*)d_in[3];
  const int* counts = (const int*)d_in[4];
  int* out_bits = (int*)d_out;
  float* ws = (float*)d_ws;

  k_minmax<<<dim3(256), dim3(256), 0, stream>>>(x, ws, out_bits);
  k_stats<<<dim3(1), dim3(256), 0, stream>>>(ws);
  k_denom<<<dim3(256), dim3(64), 0, stream>>>(T, committed, counts, ws + 512);
  k_main<<<dim3(2048), dim3(512), 0, stream>>>(x, T, labels, ws, out_bits);
  k_probe<<<dim3(2048), dim3(256), 0, stream>>>(ws);
}